// Round 3
// baseline (612.360 us; speedup 1.0000x reference)
//
#include <hip/hip_runtime.h>

// ---------------------------------------------------------------------------
// Talking-heads attention, fused. B=2, N=M=2048, D=1024, H=16, dh=64.
// R2: denom split into own kernel; j partitioned over 8 chunks (2048 blocks,
// 2 resident/CU); fp32 HW-atomic epilogue into memset-zeroed out.
// ---------------------------------------------------------------------------

typedef __attribute__((ext_vector_type(8))) short short8;
typedef __attribute__((ext_vector_type(4))) short short4v;
typedef __attribute__((ext_vector_type(4))) float float4v;
typedef unsigned short u16;

#define MFMA16(a, b, c) __builtin_amdgcn_mfma_f32_16x16x32_bf16((a), (b), (c), 0, 0, 0)

__device__ inline u16 f2bf(float f) {  // RNE f32->bf16 (inputs finite)
  unsigned u = __float_as_uint(f);
  u += 0x7FFFu + ((u >> 16) & 1u);
  return (u16)(u >> 16);
}

// ---------------------------- cast kernel ----------------------------------
__global__ __launch_bounds__(256) void cast_bf16(const float* __restrict__ in,
                                                 u16* __restrict__ out, int n) {
  int i = (blockIdx.x * 256 + threadIdx.x) * 8;
  if (i + 8 > n) return;
  float4v f0 = *(const float4v*)(in + i);
  float4v f1 = *(const float4v*)(in + i + 4);
  short8 o;
  o[0] = (short)f2bf(f0[0]); o[1] = (short)f2bf(f0[1]);
  o[2] = (short)f2bf(f0[2]); o[3] = (short)f2bf(f0[3]);
  o[4] = (short)f2bf(f1[0]); o[5] = (short)f2bf(f1[1]);
  o[6] = (short)f2bf(f1[2]); o[7] = (short)f2bf(f1[3]);
  *(short8*)(out + i) = o;
}

// ------------------------ projection GEMM ----------------------------------
template <int MODE>
__global__ __launch_bounds__(256, 4) void gemm_bt(const u16* __restrict__ A,
                                                  const u16* __restrict__ W,
                                                  u16* __restrict__ out0,
                                                  u16* __restrict__ out1) {
  __shared__ u16 As[64][40];
  __shared__ u16 Ws[64][40];
  const int t = threadIdx.x;
  const int wave = t >> 6, l = t & 63, l15 = l & 15, lq = l >> 4;
  const int r0 = blockIdx.x * 64, c0 = blockIdx.y * 64;
  const int srow = t >> 2, sch = t & 3;
  const u16* ag = A + (r0 + srow) * 1024 + sch * 8;
  const u16* wg = W + (c0 + srow) * 1024 + sch * 8;

  float4v acc[4];
#pragma unroll
  for (int i = 0; i < 4; ++i) acc[i] = (float4v){0.f, 0.f, 0.f, 0.f};

  short8 av = *(const short8*)ag;
  short8 wv = *(const short8*)wg;
  for (int kt = 0; kt < 32; ++kt) {
    __syncthreads();
    *(short8*)&As[srow][sch * 8] = av;
    *(short8*)&Ws[srow][sch * 8] = wv;
    __syncthreads();
    if (kt < 31) {
      av = *(const short8*)(ag + (kt + 1) * 32);
      wv = *(const short8*)(wg + (kt + 1) * 32);
    }
    short8 af = *(const short8*)&As[wave * 16 + l15][lq * 8];
#pragma unroll
    for (int fn = 0; fn < 4; ++fn) {
      short8 bf = *(const short8*)&Ws[fn * 16 + l15][lq * 8];
      acc[fn] = MFMA16(af, bf, acc[fn]);
    }
  }
#pragma unroll
  for (int fn = 0; fn < 4; ++fn) {
#pragma unroll
    for (int r = 0; r < 4; ++r) {
      int row = r0 + wave * 16 + lq * 4 + r;
      int col = c0 + fn * 16 + l15;
      int b = row >> 11, n = row & 2047;
      float v = acc[fn][r];
      if (MODE == 0) {
        v *= 0.125f;
        int h = col >> 6, d = col & 63;
        out0[(((b * 16 + h) * 2048 + n) << 6) + d] = f2bf(v);
      } else {
        if (col < 1024) {
          int h = col >> 6, d = col & 63;
          out0[(((b * 16 + h) * 2048 + n) << 6) + d] = f2bf(v);
        } else {
          int cc = col - 1024;
          int h = cc >> 6, d = cc & 63;
          out1[(((b * 16 + h) * 2048 + n) << 6) + d] = f2bf(v);
        }
      }
    }
  }
}

// --------------------------- V transpose -----------------------------------
__global__ __launch_bounds__(256) void transpose_v(const u16* __restrict__ vh,
                                                   u16* __restrict__ vt) {
  __shared__ u16 tile[64][72];
  const int t = threadIdx.x;
  const int j0 = blockIdx.x * 64, h = blockIdx.y, b = blockIdx.z;
  const u16* src = vh + (((b * 16 + h) * 2048 + j0) << 6);
  int row = t >> 2, c = t & 3;
  short8 v0 = *(const short8*)(src + row * 64 + c * 8);
  short8 v1 = *(const short8*)(src + row * 64 + (c + 4) * 8);
  *(short8*)&tile[row][c * 8] = v0;
  *(short8*)&tile[row][(c + 4) * 8] = v1;
  __syncthreads();
  int d = t >> 2, jc = t & 3;
  short8 o0, o1;
#pragma unroll
  for (int jj = 0; jj < 8; ++jj) o0[jj] = (short)tile[jc * 16 + jj][d];
#pragma unroll
  for (int jj = 0; jj < 8; ++jj) o1[jj] = (short)tile[jc * 16 + 8 + jj][d];
  u16* dst = vt + ((b * 16 + h) * 64 + d) * 2048 + j0 + jc * 16;
  *(short8*)dst = o0;
  *(short8*)(dst + 8) = o1;
}

// --------------------- softmax denominator kernel --------------------------
// grid (bh=32, itile=32), block 256 = 4 waves; wave handles 16 i-rows,
// streams all K. Writes negl[bh][i] = -log(sum_j exp(s)). No LDS/barriers.
__global__ __launch_bounds__(256) void denom_kernel(const u16* __restrict__ qh,
                                                    const u16* __restrict__ kh,
                                                    float* __restrict__ negl) {
  const int bh = blockIdx.x;
  const int i0 = blockIdx.y * 64 + (threadIdx.x >> 6) * 16;
  const int l = threadIdx.x & 63, l15 = l & 15, lq = l >> 4;
  const u16* qbase = qh + ((bh * 2048 + i0) << 6);
  short8 qf0 = *(const short8*)(qbase + l15 * 64 + lq * 8);
  short8 qf1 = *(const short8*)(qbase + l15 * 64 + 32 + lq * 8);
  const u16* kbase = kh + ((bh * 2048) << 6);

  float ps0 = 0.f, ps1 = 0.f, ps2 = 0.f, ps3 = 0.f;
  short8 k00 = *(const short8*)(kbase + l15 * 64 + lq * 8);
  short8 k01 = *(const short8*)(kbase + l15 * 64 + 32 + lq * 8);
  short8 k10 = *(const short8*)(kbase + (16 + l15) * 64 + lq * 8);
  short8 k11 = *(const short8*)(kbase + (16 + l15) * 64 + 32 + lq * 8);
  for (int jt = 0; jt < 64; ++jt) {
    short8 n00, n01, n10, n11;
    if (jt < 63) {
      const u16* kp = kbase + (((jt + 1) * 32) << 6);
      n00 = *(const short8*)(kp + l15 * 64 + lq * 8);
      n01 = *(const short8*)(kp + l15 * 64 + 32 + lq * 8);
      n10 = *(const short8*)(kp + (16 + l15) * 64 + lq * 8);
      n11 = *(const short8*)(kp + (16 + l15) * 64 + 32 + lq * 8);
    }
    float4v s0 = {0.f, 0.f, 0.f, 0.f}, s1 = {0.f, 0.f, 0.f, 0.f};
    s0 = MFMA16(qf0, k00, s0);
    s0 = MFMA16(qf1, k01, s0);
    s1 = MFMA16(qf0, k10, s1);
    s1 = MFMA16(qf1, k11, s1);
    ps0 += __expf(s0[0]) + __expf(s1[0]);
    ps1 += __expf(s0[1]) + __expf(s1[1]);
    ps2 += __expf(s0[2]) + __expf(s1[2]);
    ps3 += __expf(s0[3]) + __expf(s1[3]);
    k00 = n00; k01 = n01; k10 = n10; k11 = n11;
  }
#pragma unroll
  for (int d = 1; d < 16; d <<= 1) {
    ps0 += __shfl_xor(ps0, d);
    ps1 += __shfl_xor(ps1, d);
    ps2 += __shfl_xor(ps2, d);
    ps3 += __shfl_xor(ps3, d);
  }
  if (l15 == 0) {
    float* o = negl + bh * 2048 + i0 + lq * 4;
    o[0] = -logf(ps0);
    o[1] = -logf(ps1);
    o[2] = -logf(ps2);
    o[3] = -logf(ps3);
  }
}

// ------------------------- fused attention ---------------------------------
// grid (itile=128, jchunk=8, b=2) = 2048 blocks, 16 waves (wave == head).
// Each block: 16 q-rows x 256 j, single pass (denoms precomputed), partial O
// accumulated into out via fp32 HW atomics (out memset to 0 first).
__global__ __launch_bounds__(1024) void attn_fused(
    const u16* __restrict__ qh, const u16* __restrict__ kh,
    const u16* __restrict__ vt, const float* __restrict__ negl,
    const float* __restrict__ wtalk, const float* __restrict__ gamma,
    const float* __restrict__ beta, float* __restrict__ out) {
  __shared__ u16 P_lds[512 * 36];      // [e=i*32+jl][36]; cols 16..35 stay 0
  __shared__ u16 Y_lds[16 * 16 * 32];  // [g][i][jl]

  const int tid = threadIdx.x;
  const int wv = tid >> 6;  // wave id == head
  const int l = tid & 63, l15 = l & 15, lq = l >> 4;
  const int i0 = blockIdx.x * 16;
  const int jc0 = blockIdx.y * 256;
  const int b = blockIdx.z;
  const int bh = b * 16 + wv;

  for (int z = tid; z < 512 * 36; z += 1024) P_lds[z] = 0;

  // Wtalk A-fragment: A[g=l15][h=lq*8+t], zero for h>=16 (K padded to 32)
  short8 wfrag;
#pragma unroll
  for (int t8 = 0; t8 < 8; ++t8) {
    int h = lq * 8 + t8;
    float wval = (h < 16) ? wtalk[l15 * 16 + h] : 0.f;
    wfrag[t8] = (short)f2bf(wval);
  }
  float gam[4], bet[4], bc[4];
#pragma unroll
  for (int r = 0; r < 4; ++r) {
    gam[r] = gamma[lq * 4 + r];
    bet[r] = beta[lq * 4 + r];
    bc[r] = negl[bh * 2048 + i0 + lq * 4 + r];
  }

  const u16* qbase = qh + ((bh * 2048 + i0) << 6);
  short8 qf0 = *(const short8*)(qbase + l15 * 64 + lq * 8);
  short8 qf1 = *(const short8*)(qbase + l15 * 64 + 32 + lq * 8);
  const u16* kbase = kh + ((bh * 2048) << 6);
  const u16* vbase = vt + (bh * 64) * 2048;

  __syncthreads();  // P zero-init visible

  float4v acc0 = {0.f, 0.f, 0.f, 0.f}, acc1 = acc0, acc2 = acc0, acc3 = acc0;
  for (int jt = 0; jt < 8; ++jt) {
    const int j0 = jc0 + jt * 32;
    const u16* kp = kbase + (j0 << 6);
    short8 a00 = *(const short8*)(kp + l15 * 64 + lq * 8);
    short8 a01 = *(const short8*)(kp + l15 * 64 + 32 + lq * 8);
    short8 a10 = *(const short8*)(kp + (16 + l15) * 64 + lq * 8);
    short8 a11 = *(const short8*)(kp + (16 + l15) * 64 + 32 + lq * 8);
    float4v s0 = {0.f, 0.f, 0.f, 0.f}, s1 = {0.f, 0.f, 0.f, 0.f};
    s0 = MFMA16(qf0, a00, s0);
    s0 = MFMA16(qf1, a01, s0);
    s1 = MFMA16(qf0, a10, s1);
    s1 = MFMA16(qf1, a11, s1);
    // P = exp(S - log l), bf16, scatter to P_lds[e][h]
    {
      int ebase = (lq * 4) * 32 + l15;
#pragma unroll
      for (int r = 0; r < 4; ++r) {
        float p0 = __expf(s0[r] + bc[r]);
        float p1 = __expf(s1[r] + bc[r]);
        P_lds[(ebase + r * 32) * 36 + wv] = f2bf(p0);
        P_lds[(ebase + r * 32 + 16) * 36 + wv] = f2bf(p1);
      }
    }
    __syncthreads();
    // V fragments early (independent of LDS phase)
    const u16* vp = vbase + j0 + lq * 8;
    short8 v0 = *(const short8*)(vp + (l15) * 2048);
    short8 v1 = *(const short8*)(vp + (16 + l15) * 2048);
    short8 v2 = *(const short8*)(vp + (32 + l15) * 2048);
    short8 v3 = *(const short8*)(vp + (48 + l15) * 2048);
    // talk: wave wv covers e in [wv*32, wv*32+32)  (i-row == wv)
    float4v t0 = {0.f, 0.f, 0.f, 0.f}, t1 = {0.f, 0.f, 0.f, 0.f};
    {
      int e00 = wv * 32 + l15;
      int e10 = wv * 32 + 16 + l15;
      const u16* p0p = &P_lds[e00 * 36 + lq * 8];
      const u16* p1p = &P_lds[e10 * 36 + lq * 8];
      short4v x0 = *(const short4v*)p0p;
      short4v x1 = *(const short4v*)(p0p + 4);
      short4v y0 = *(const short4v*)p1p;
      short4v y1 = *(const short4v*)(p1p + 4);
      short8 pb0 = __builtin_shufflevector(x0, x1, 0, 1, 2, 3, 4, 5, 6, 7);
      short8 pb1 = __builtin_shufflevector(y0, y1, 0, 1, 2, 3, 4, 5, 6, 7);
      t0 = MFMA16(wfrag, pb0, t0);
      t1 = MFMA16(wfrag, pb1, t1);
    }
    // head-LN per (i,j) column, write Y bf16
#pragma unroll
    for (int c2 = 0; c2 < 2; ++c2) {
      float4v tt = c2 ? t1 : t0;
      float sum = tt[0] + tt[1] + tt[2] + tt[3];
      sum += __shfl_xor(sum, 16);
      sum += __shfl_xor(sum, 32);
      float mu = sum * 0.0625f;
      float ss = tt[0] * tt[0] + tt[1] * tt[1] + tt[2] * tt[2] + tt[3] * tt[3];
      ss += __shfl_xor(ss, 16);
      ss += __shfl_xor(ss, 32);
      float var = ss * 0.0625f - mu * mu;
      float rs = rsqrtf(var + 1e-5f);
#pragma unroll
      for (int r = 0; r < 4; ++r) {
        float y = (tt[r] - mu) * rs * gam[r] + bet[r];
        Y_lds[((lq * 4 + r) * 16 + wv) * 32 + c2 * 16 + l15] = f2bf(y);
      }
    }
    __syncthreads();
    // PV (head wv)
    short8 yf = *(const short8*)&Y_lds[(wv * 16 + l15) * 32 + lq * 8];
    acc0 = MFMA16(yf, v0, acc0);
    acc1 = MFMA16(yf, v1, acc1);
    acc2 = MFMA16(yf, v2, acc2);
    acc3 = MFMA16(yf, v3, acc3);
  }
  // epilogue: atomic-accumulate partial O: out[b][i0+i][wv*64 + d]
  float* ob = out + (b * 2048 + i0) * 1024 + wv * 64;
#pragma unroll
  for (int r = 0; r < 4; ++r) {
    float* orow = ob + (lq * 4 + r) * 1024;
    unsafeAtomicAdd(orow + l15, acc0[r]);
    unsafeAtomicAdd(orow + 16 + l15, acc1[r]);
    unsafeAtomicAdd(orow + 32 + l15, acc2[r]);
    unsafeAtomicAdd(orow + 48 + l15, acc3[r]);
  }
}

// ----------------------------- launcher ------------------------------------
extern "C" void kernel_launch(void* const* d_in, const int* in_sizes, int n_in,
                              void* d_out, int out_size, void* d_ws,
                              size_t ws_size, hipStream_t stream) {
  const float* x = (const float*)d_in[0];
  const float* ctx = (const float*)d_in[1];
  const float* Wq = (const float*)d_in[2];
  const float* Wkv = (const float*)d_in[3];
  const float* Wtalk = (const float*)d_in[4];
  const float* gam = (const float*)d_in[5];
  const float* bet = (const float*)d_in[6];
  float* out = (float*)d_out;

  u16* xb = (u16*)d_ws;            // 4  Mi elems
  u16* cb = xb + 4194304;          // 4  Mi
  u16* wqb = cb + 4194304;         // 1  Mi
  u16* wkvb = wqb + 1048576;       // 2  Mi
  u16* qhb = wkvb + 2097152;       // 4  Mi  [b][h][n][64]
  u16* khb = qhb + 4194304;        // 4  Mi  [b][h][j][64]
  u16* vhb = khb + 4194304;        // 4  Mi  [b][h][j][64]
  u16* vtb = vhb + 4194304;        // 4  Mi  [b][h][d][2048]
  float* negl = (float*)(vtb + 4194304);  // 64 Ki fp32

  hipMemsetAsync(out, 0, 2 * 2048 * 1024 * sizeof(float), stream);

  cast_bf16<<<2048, 256, 0, stream>>>(x, xb, 4194304);
  cast_bf16<<<2048, 256, 0, stream>>>(ctx, cb, 4194304);
  cast_bf16<<<512, 256, 0, stream>>>(Wq, wqb, 1048576);
  cast_bf16<<<1024, 256, 0, stream>>>(Wkv, wkvb, 2097152);

  gemm_bt<0><<<dim3(64, 16), 256, 0, stream>>>(xb, wqb, qhb, nullptr);
  gemm_bt<1><<<dim3(64, 32), 256, 0, stream>>>(cb, wkvb, khb, vhb);

  transpose_v<<<dim3(32, 16, 2), 256, 0, stream>>>(vhb, vtb);

  denom_kernel<<<dim3(32, 32), 256, 0, stream>>>(qhb, khb, negl);

  attn_fused<<<dim3(128, 8, 2), 1024, 0, stream>>>(qhb, khb, vtb, negl, Wtalk,
                                                   gam, bet, out);
}

// Round 4
// 506.734 us; speedup vs baseline: 1.2084x; 1.2084x over previous
//
#include <hip/hip_runtime.h>

// ---------------------------------------------------------------------------
// Talking-heads attention, fused. B=2, N=M=2048, D=1024, H=16, dh=64.
// R4: full-j blocks (grid 256, 1/CU), in-kernel pass1, pass2 with ONE barrier
// per j-tile (double-buffered P/Y + PV pipelined one iter behind), K/V
// prefetched. No atomics, no denom kernel, no memset.
// ---------------------------------------------------------------------------

typedef __attribute__((ext_vector_type(8))) short short8;
typedef __attribute__((ext_vector_type(4))) short short4v;
typedef __attribute__((ext_vector_type(4))) float float4v;
typedef unsigned short u16;

#define MFMA16(a, b, c) __builtin_amdgcn_mfma_f32_16x16x32_bf16((a), (b), (c), 0, 0, 0)

__device__ inline u16 f2bf(float f) {  // RNE f32->bf16 (inputs finite)
  unsigned u = __float_as_uint(f);
  u += 0x7FFFu + ((u >> 16) & 1u);
  return (u16)(u >> 16);
}

// ---------------------------- cast kernel ----------------------------------
__global__ __launch_bounds__(256) void cast_bf16(const float* __restrict__ in,
                                                 u16* __restrict__ out, int n) {
  int i = (blockIdx.x * 256 + threadIdx.x) * 8;
  if (i + 8 > n) return;
  float4v f0 = *(const float4v*)(in + i);
  float4v f1 = *(const float4v*)(in + i + 4);
  short8 o;
  o[0] = (short)f2bf(f0[0]); o[1] = (short)f2bf(f0[1]);
  o[2] = (short)f2bf(f0[2]); o[3] = (short)f2bf(f0[3]);
  o[4] = (short)f2bf(f1[0]); o[5] = (short)f2bf(f1[1]);
  o[6] = (short)f2bf(f1[2]); o[7] = (short)f2bf(f1[3]);
  *(short8*)(out + i) = o;
}

// ------------------------ projection GEMM ----------------------------------
template <int MODE>
__global__ __launch_bounds__(256, 4) void gemm_bt(const u16* __restrict__ A,
                                                  const u16* __restrict__ W,
                                                  u16* __restrict__ out0,
                                                  u16* __restrict__ out1) {
  __shared__ u16 As[64][40];
  __shared__ u16 Ws[64][40];
  const int t = threadIdx.x;
  const int wave = t >> 6, l = t & 63, l15 = l & 15, lq = l >> 4;
  const int r0 = blockIdx.x * 64, c0 = blockIdx.y * 64;
  const int srow = t >> 2, sch = t & 3;
  const u16* ag = A + (r0 + srow) * 1024 + sch * 8;
  const u16* wg = W + (c0 + srow) * 1024 + sch * 8;

  float4v acc[4];
#pragma unroll
  for (int i = 0; i < 4; ++i) acc[i] = (float4v){0.f, 0.f, 0.f, 0.f};

  short8 av = *(const short8*)ag;
  short8 wv = *(const short8*)wg;
  for (int kt = 0; kt < 32; ++kt) {
    __syncthreads();
    *(short8*)&As[srow][sch * 8] = av;
    *(short8*)&Ws[srow][sch * 8] = wv;
    __syncthreads();
    if (kt < 31) {
      av = *(const short8*)(ag + (kt + 1) * 32);
      wv = *(const short8*)(wg + (kt + 1) * 32);
    }
    short8 af = *(const short8*)&As[wave * 16 + l15][lq * 8];
#pragma unroll
    for (int fn = 0; fn < 4; ++fn) {
      short8 bf = *(const short8*)&Ws[fn * 16 + l15][lq * 8];
      acc[fn] = MFMA16(af, bf, acc[fn]);
    }
  }
#pragma unroll
  for (int fn = 0; fn < 4; ++fn) {
#pragma unroll
    for (int r = 0; r < 4; ++r) {
      int row = r0 + wave * 16 + lq * 4 + r;
      int col = c0 + fn * 16 + l15;
      int b = row >> 11, n = row & 2047;
      float v = acc[fn][r];
      if (MODE == 0) {
        v *= 0.125f;
        int h = col >> 6, d = col & 63;
        out0[(((b * 16 + h) * 2048 + n) << 6) + d] = f2bf(v);
      } else {
        if (col < 1024) {
          int h = col >> 6, d = col & 63;
          out0[(((b * 16 + h) * 2048 + n) << 6) + d] = f2bf(v);
        } else {
          int cc = col - 1024;
          int h = cc >> 6, d = cc & 63;
          out1[(((b * 16 + h) * 2048 + n) << 6) + d] = f2bf(v);
        }
      }
    }
  }
}

// --------------------------- V transpose -----------------------------------
__global__ __launch_bounds__(256) void transpose_v(const u16* __restrict__ vh,
                                                   u16* __restrict__ vt) {
  __shared__ u16 tile[64][72];
  const int t = threadIdx.x;
  const int j0 = blockIdx.x * 64, h = blockIdx.y, b = blockIdx.z;
  const u16* src = vh + (((b * 16 + h) * 2048 + j0) << 6);
  int row = t >> 2, c = t & 3;
  short8 v0 = *(const short8*)(src + row * 64 + c * 8);
  short8 v1 = *(const short8*)(src + row * 64 + (c + 4) * 8);
  *(short8*)&tile[row][c * 8] = v0;
  *(short8*)&tile[row][(c + 4) * 8] = v1;
  __syncthreads();
  int d = t >> 2, jc = t & 3;
  short8 o0, o1;
#pragma unroll
  for (int jj = 0; jj < 8; ++jj) o0[jj] = (short)tile[jc * 16 + jj][d];
#pragma unroll
  for (int jj = 0; jj < 8; ++jj) o1[jj] = (short)tile[jc * 16 + 8 + jj][d];
  u16* dst = vt + ((b * 16 + h) * 64 + d) * 2048 + j0 + jc * 16;
  *(short8*)dst = o0;
  *(short8*)(dst + 8) = o1;
}

// ------------------------- fused attention ---------------------------------
// grid (itile=128, b=2) = 256 blocks, 16 waves (wave == head), full j.
// Pass 1: softmax denominators (no barriers, K prefetched).
// Pass 2: one barrier/iter; P,Y double-buffered; PV lags one iteration.
__global__ __launch_bounds__(1024) void attn_fused(
    const u16* __restrict__ qh, const u16* __restrict__ kh,
    const u16* __restrict__ vt, const float* __restrict__ wtalk,
    const float* __restrict__ gamma, const float* __restrict__ beta,
    float* __restrict__ out) {
  __shared__ u16 P_lds[2][512 * 36];   // [buf][e=i*32+jl][36]; cols 16.. = 0
  __shared__ u16 Y_lds[2][16 * 16 * 36];  // [buf][g][i][36]

  const int tid = threadIdx.x;
  const int wv = tid >> 6;  // wave id == head
  const int l = tid & 63, l15 = l & 15, lq = l >> 4;
  const int i0 = blockIdx.x * 16;
  const int b = blockIdx.y;
  const int bh = b * 16 + wv;

  {  // zero both P buffers (pad cols h>=16 must be 0 for the K=32 talk MFMA)
    u16* pz = &P_lds[0][0];
    for (int z = tid; z < 2 * 512 * 36; z += 1024) pz[z] = 0;
  }

  // Wtalk A-fragment: A[g=l15][h=lq*8+t], zero for h>=16 (K padded to 32)
  short8 wfrag;
#pragma unroll
  for (int t8 = 0; t8 < 8; ++t8) {
    int h = lq * 8 + t8;
    float wval = (h < 16) ? wtalk[l15 * 16 + h] : 0.f;
    wfrag[t8] = (short)f2bf(wval);
  }
  float gam[4], bet[4];
#pragma unroll
  for (int r = 0; r < 4; ++r) {
    gam[r] = gamma[lq * 4 + r];
    bet[r] = beta[lq * 4 + r];
  }

  const u16* qbase = qh + ((bh * 2048 + i0) << 6);
  short8 qf0 = *(const short8*)(qbase + l15 * 64 + lq * 8);
  short8 qf1 = *(const short8*)(qbase + l15 * 64 + 32 + lq * 8);
  const u16* kbase = kh + ((bh * 2048) << 6);
  const u16* vbase = vt + (bh * 64) * 2048;

  __syncthreads();  // P zero-init visible before any pass-2 P-write

  // ---- pass 1: denominators (scores O(10): no max subtraction needed) ----
  float ps0 = 0.f, ps1 = 0.f, ps2 = 0.f, ps3 = 0.f;
  short8 k00 = *(const short8*)(kbase + l15 * 64 + lq * 8);
  short8 k01 = *(const short8*)(kbase + l15 * 64 + 32 + lq * 8);
  short8 k10 = *(const short8*)(kbase + (16 + l15) * 64 + lq * 8);
  short8 k11 = *(const short8*)(kbase + (16 + l15) * 64 + 32 + lq * 8);
  for (int jt = 0; jt < 64; ++jt) {
    short8 n00, n01, n10, n11;
    if (jt < 63) {
      const u16* kp = kbase + (((jt + 1) * 32) << 6);
      n00 = *(const short8*)(kp + l15 * 64 + lq * 8);
      n01 = *(const short8*)(kp + l15 * 64 + 32 + lq * 8);
      n10 = *(const short8*)(kp + (16 + l15) * 64 + lq * 8);
      n11 = *(const short8*)(kp + (16 + l15) * 64 + 32 + lq * 8);
    }
    float4v s0 = {0.f, 0.f, 0.f, 0.f}, s1 = {0.f, 0.f, 0.f, 0.f};
    s0 = MFMA16(qf0, k00, s0);
    s0 = MFMA16(qf1, k01, s0);
    s1 = MFMA16(qf0, k10, s1);
    s1 = MFMA16(qf1, k11, s1);
    ps0 += __expf(s0[0]) + __expf(s1[0]);
    ps1 += __expf(s0[1]) + __expf(s1[1]);
    ps2 += __expf(s0[2]) + __expf(s1[2]);
    ps3 += __expf(s0[3]) + __expf(s1[3]);
    k00 = n00; k01 = n01; k10 = n10; k11 = n11;
  }
#pragma unroll
  for (int d = 1; d < 16; d <<= 1) {
    ps0 += __shfl_xor(ps0, d);
    ps1 += __shfl_xor(ps1, d);
    ps2 += __shfl_xor(ps2, d);
    ps3 += __shfl_xor(ps3, d);
  }
  float bc[4];
  bc[0] = -logf(ps0); bc[1] = -logf(ps1);
  bc[2] = -logf(ps2); bc[3] = -logf(ps3);

  // ---- pass 2: one barrier per iter, PV pipelined one iter behind ----
  float4v acc0 = {0.f, 0.f, 0.f, 0.f}, acc1 = acc0, acc2 = acc0, acc3 = acc0;
  // K fragments for tile 0 (current)
  short8 kc00 = *(const short8*)(kbase + l15 * 64 + lq * 8);
  short8 kc01 = *(const short8*)(kbase + l15 * 64 + 32 + lq * 8);
  short8 kc10 = *(const short8*)(kbase + (16 + l15) * 64 + lq * 8);
  short8 kc11 = *(const short8*)(kbase + (16 + l15) * 64 + 32 + lq * 8);
  short8 v0, v1, v2, v3;  // V for the *previous* tile (PV lags by 1)

  for (int jt = 0; jt <= 64; ++jt) {
    const int buf = jt & 1, pbuf = (jt - 1) & 1;
    // V fragments for tile jt-1 (used in PV at the end of this iter)
    if (jt >= 1) {
      const u16* vp = vbase + (jt - 1) * 32 + lq * 8;
      v0 = *(const short8*)(vp + (l15) * 2048);
      v1 = *(const short8*)(vp + (16 + l15) * 2048);
      v2 = *(const short8*)(vp + (32 + l15) * 2048);
      v3 = *(const short8*)(vp + (48 + l15) * 2048);
    }
    // K prefetch for tile jt+1
    short8 kn00, kn01, kn10, kn11;
    if (jt + 1 < 64) {
      const u16* kp = kbase + (((jt + 1) * 32) << 6);
      kn00 = *(const short8*)(kp + l15 * 64 + lq * 8);
      kn01 = *(const short8*)(kp + l15 * 64 + 32 + lq * 8);
      kn10 = *(const short8*)(kp + (16 + l15) * 64 + lq * 8);
      kn11 = *(const short8*)(kp + (16 + l15) * 64 + 32 + lq * 8);
    }
    if (jt < 64) {
      // QK for tile jt
      float4v s0 = {0.f, 0.f, 0.f, 0.f}, s1 = {0.f, 0.f, 0.f, 0.f};
      s0 = MFMA16(qf0, kc00, s0);
      s0 = MFMA16(qf1, kc01, s0);
      s1 = MFMA16(qf0, kc10, s1);
      s1 = MFMA16(qf1, kc11, s1);
      // P = exp(S - log l) -> bf16 -> P_lds[buf][e][wv]
      int ebase = (lq * 4) * 32 + l15;
#pragma unroll
      for (int r = 0; r < 4; ++r) {
        float p0 = __expf(s0[r] + bc[r]);
        float p1 = __expf(s1[r] + bc[r]);
        P_lds[buf][(ebase + r * 32) * 36 + wv] = f2bf(p0);
        P_lds[buf][(ebase + r * 32 + 16) * 36 + wv] = f2bf(p1);
      }
    }
    __syncthreads();  // the only barrier: P(jt) visible; Y(jt-1) visible
    if (jt < 64) {
      // talk: wave wv covers e in [wv*32, wv*32+32)
      float4v t0 = {0.f, 0.f, 0.f, 0.f}, t1 = {0.f, 0.f, 0.f, 0.f};
      {
        int e00 = wv * 32 + l15;
        int e10 = wv * 32 + 16 + l15;
        const u16* p0p = &P_lds[buf][e00 * 36 + lq * 8];
        const u16* p1p = &P_lds[buf][e10 * 36 + lq * 8];
        short4v x0 = *(const short4v*)p0p;
        short4v x1 = *(const short4v*)(p0p + 4);
        short4v y0 = *(const short4v*)p1p;
        short4v y1 = *(const short4v*)(p1p + 4);
        short8 pb0 = __builtin_shufflevector(x0, x1, 0, 1, 2, 3, 4, 5, 6, 7);
        short8 pb1 = __builtin_shufflevector(y0, y1, 0, 1, 2, 3, 4, 5, 6, 7);
        t0 = MFMA16(wfrag, pb0, t0);
        t1 = MFMA16(wfrag, pb1, t1);
      }
      // head-LN per (i,j) column, write Y bf16 to Y_lds[buf]
#pragma unroll
      for (int c2 = 0; c2 < 2; ++c2) {
        float4v tt = c2 ? t1 : t0;
        float sum = tt[0] + tt[1] + tt[2] + tt[3];
        sum += __shfl_xor(sum, 16);
        sum += __shfl_xor(sum, 32);
        float mu = sum * 0.0625f;
        float ss = tt[0] * tt[0] + tt[1] * tt[1] + tt[2] * tt[2] + tt[3] * tt[3];
        ss += __shfl_xor(ss, 16);
        ss += __shfl_xor(ss, 32);
        float var = ss * 0.0625f - mu * mu;
        float rs = rsqrtf(var + 1e-5f);
#pragma unroll
        for (int r = 0; r < 4; ++r) {
          float y = (tt[r] - mu) * rs * gam[r] + bet[r];
          Y_lds[buf][((lq * 4 + r) * 16 + wv) * 36 + c2 * 16 + l15] = f2bf(y);
        }
      }
    }
    if (jt >= 1) {
      // PV for tile jt-1 (Y written by all waves before this iter's barrier)
      short8 yf = *(const short8*)&Y_lds[pbuf][(wv * 16 + l15) * 36 + lq * 8];
      acc0 = MFMA16(yf, v0, acc0);
      acc1 = MFMA16(yf, v1, acc1);
      acc2 = MFMA16(yf, v2, acc2);
      acc3 = MFMA16(yf, v3, acc3);
    }
    kc00 = kn00; kc01 = kn01; kc10 = kn10; kc11 = kn11;
  }
  // epilogue: plain stores, block owns (b, i0..i0+16) exclusively
  float* ob = out + (b * 2048 + i0) * 1024 + wv * 64;
#pragma unroll
  for (int r = 0; r < 4; ++r) {
    float* orow = ob + (lq * 4 + r) * 1024;
    orow[l15] = acc0[r];
    orow[16 + l15] = acc1[r];
    orow[32 + l15] = acc2[r];
    orow[48 + l15] = acc3[r];
  }
}

// ----------------------------- launcher ------------------------------------
extern "C" void kernel_launch(void* const* d_in, const int* in_sizes, int n_in,
                              void* d_out, int out_size, void* d_ws,
                              size_t ws_size, hipStream_t stream) {
  const float* x = (const float*)d_in[0];
  const float* ctx = (const float*)d_in[1];
  const float* Wq = (const float*)d_in[2];
  const float* Wkv = (const float*)d_in[3];
  const float* Wtalk = (const float*)d_in[4];
  const float* gam = (const float*)d_in[5];
  const float* bet = (const float*)d_in[6];
  float* out = (float*)d_out;

  u16* xb = (u16*)d_ws;            // 4  Mi elems
  u16* cb = xb + 4194304;          // 4  Mi
  u16* wqb = cb + 4194304;         // 1  Mi
  u16* wkvb = wqb + 1048576;       // 2  Mi
  u16* qhb = wkvb + 2097152;       // 4  Mi  [b][h][n][64]
  u16* khb = qhb + 4194304;        // 4  Mi  [b][h][j][64]
  u16* vhb = khb + 4194304;        // 4  Mi  [b][h][j][64]
  u16* vtb = vhb + 4194304;        // 4  Mi  [b][h][d][2048]

  cast_bf16<<<2048, 256, 0, stream>>>(x, xb, 4194304);
  cast_bf16<<<2048, 256, 0, stream>>>(ctx, cb, 4194304);
  cast_bf16<<<512, 256, 0, stream>>>(Wq, wqb, 1048576);
  cast_bf16<<<1024, 256, 0, stream>>>(Wkv, wkvb, 2097152);

  gemm_bt<0><<<dim3(64, 16), 256, 0, stream>>>(xb, wqb, qhb, nullptr);
  gemm_bt<1><<<dim3(64, 32), 256, 0, stream>>>(cb, wkvb, khb, vhb);

  transpose_v<<<dim3(32, 16, 2), 256, 0, stream>>>(vhb, vtb);

  attn_fused<<<dim3(128, 2), 1024, 0, stream>>>(qhb, khb, vtb, Wtalk, gam, bet,
                                                out);
}